// Round 8
// baseline (1049.528 us; speedup 1.0000x reference)
//
#include <hip/hip_runtime.h>
#include <hip/hip_bf16.h>

constexpr int B_ = 8, N_ = 4096, M_ = 77;
constexpr int CD_ = 768, H_ = 8, DH_ = 64, IN_ = 512;

typedef _Float16 f16x4 __attribute__((ext_vector_type(4)));
typedef _Float16 f16x8 __attribute__((ext_vector_type(8)));
typedef float f32x4 __attribute__((ext_vector_type(4)));

// ------------------------------------------------------------- K/V projection
// grid (11, B), block 512. Each block: 7 context rows -> K,V columns. fp32.
__global__ __launch_bounds__(512) void kv_proj(const float* __restrict__ ctx,
                                               const float* __restrict__ Wk,
                                               const float* __restrict__ Wv,
                                               float* __restrict__ Kbuf,
                                               float* __restrict__ Vbuf) {
    __shared__ float cs[7 * CD_];
    const int b = blockIdx.y;
    const int m0 = blockIdx.x * 7;
    const int tid = threadIdx.x;
    const float* src = ctx + ((size_t)b * M_ + m0) * CD_;
    for (int f = tid; f < 7 * CD_; f += 512) cs[f] = src[f];
    __syncthreads();
    float aK[7], aV[7];
#pragma unroll
    for (int i = 0; i < 7; ++i) { aK[i] = 0.f; aV[i] = 0.f; }
    const int j = tid;
    for (int c = 0; c < CD_; ++c) {
        const float wk = Wk[(size_t)c * IN_ + j];
        const float wv = Wv[(size_t)c * IN_ + j];
#pragma unroll
        for (int i = 0; i < 7; ++i) {
            aK[i] = fmaf(cs[i * CD_ + c], wk, aK[i]);
            aV[i] = fmaf(cs[i * CD_ + c], wv, aV[i]);
        }
    }
    const int h = j >> 6, d = j & 63;
#pragma unroll
    for (int i = 0; i < 7; ++i) {
        const size_t o = (((size_t)b * H_ + h) * M_ + (m0 + i)) * DH_ + d;
        Kbuf[o] = aK[i];
        Vbuf[o] = aV[i];
    }
}

// ------------------------------------------------------------- weight prep
// Transpose W[512,512] -> Wt[col][k] and split fp32 -> f16 hi/lo. grid (8,8,2).
__global__ __launch_bounds__(256) void wsplit(const float* __restrict__ Wq,
                                              const float* __restrict__ Wo,
                                              _Float16* __restrict__ qh, _Float16* __restrict__ ql,
                                              _Float16* __restrict__ oh, _Float16* __restrict__ ol) {
    __shared__ float T[64][65];
    const float* W = blockIdx.z ? Wo : Wq;
    _Float16* Hh = blockIdx.z ? oh : qh;
    _Float16* Hl = blockIdx.z ? ol : ql;
    const int k0 = blockIdx.y * 64, c0 = blockIdx.x * 64;
    const int tid = threadIdx.x;
    for (int f = tid; f < 4096; f += 256) {
        const int i = f >> 6, j = f & 63;
        T[i][j] = W[(size_t)(k0 + i) * IN_ + c0 + j];
    }
    __syncthreads();
    for (int f = tid; f < 4096; f += 256) {
        const int ci = f >> 6, kj = f & 63;
        const float v = T[kj][ci];
        const _Float16 h = (_Float16)v;
        const _Float16 l = (_Float16)(v - (float)h);
        Hh[(size_t)(c0 + ci) * IN_ + k0 + kj] = h;
        Hl[(size_t)(c0 + ci) * IN_ + k0 + kj] = l;
    }
}

// ------------------------------------------------------------- MFMA GEMM
// C[32768,512] = A[32768,512] @ W[512,512] (+bias), split-f16 3-product MFMA.
// grid 1024 linear, block 256 (4 waves, 2x2). Tile 128x128, BK=64.
// XCD-swizzled tile ids; software-pipelined global->reg prefetch (T14).
// LDS: hi/lo f16 tiles, XOR-swizzled (k ^= (row&7)<<3) -> conflict-free b128.
__global__ __launch_bounds__(256) void gemm_mfma(const float* __restrict__ A,
                                                 const _Float16* __restrict__ Wth,
                                                 const _Float16* __restrict__ Wtl,
                                                 const float* __restrict__ bias,
                                                 float* __restrict__ C) {
    constexpr int BK = 64;
    __shared__ __align__(16) _Float16 Ah[128 * BK];
    __shared__ __align__(16) _Float16 Al[128 * BK];
    __shared__ __align__(16) _Float16 Bh[128 * BK];
    __shared__ __align__(16) _Float16 Bl[128 * BK];
    const int tid = threadIdx.x;
    // XCD swizzle: XCD r owns row-stripes 32r..32r+31 (all 4 col-tiles) -> A
    // stripe fetched once per XCD; W (1MB) is L2-resident on every XCD.
    const int hw = blockIdx.x;
    const int logical = (hw & 7) * 128 + (hw >> 3);
    const int col0 = (logical & 3) * 128;
    const int row0 = (logical >> 2) * 128;
    const int lane = tid & 63;
    const int wid = tid >> 6;
    const int wr = wid >> 1, wc = wid & 1;           // wave 64x64 sub-tile
    const int fr = lane & 15, fq = lane >> 4;

    // staging: thread -> (row 0..127, k-half 0|32)
    const int srow = tid >> 1;
    const int skh = (tid & 1) * 32;
    const int sxor = (srow & 7) << 3;

    // fragment read swizzle; row&7 == fr&7 (row offsets are multiples of 8)
    const int axor = (fr & 7) << 3;

    const float* aptr0 = A + (size_t)(row0 + srow) * IN_ + skh;
    const _Float16* bhp0 = Wth + (size_t)(col0 + srow) * IN_ + skh;
    const _Float16* blp0 = Wtl + (size_t)(col0 + srow) * IN_ + skh;

    f32x4 acc[4][4];
#pragma unroll
    for (int m = 0; m < 4; ++m)
#pragma unroll
        for (int n = 0; n < 4; ++n) acc[m][n] = (f32x4){0.f, 0.f, 0.f, 0.f};

    // ---- prologue: load tile 0 into regs
    float4 av[8];
    f16x8 bhv[4], blv[4];
#pragma unroll
    for (int i = 0; i < 8; ++i)
        av[i] = *reinterpret_cast<const float4*>(aptr0 + i * 4);
#pragma unroll
    for (int i = 0; i < 4; ++i) {
        bhv[i] = *reinterpret_cast<const f16x8*>(bhp0 + i * 8);
        blv[i] = *reinterpret_cast<const f16x8*>(blp0 + i * 8);
    }

#pragma unroll
    for (int kt = 0; kt < 8; ++kt) {
        __syncthreads();   // previous compute done before overwrite
        // ---- convert + LDS write (swizzled) from registers
#pragma unroll
        for (int i = 0; i < 8; ++i) {
            const float4 v = av[i];
            const _Float16 h0 = (_Float16)v.x, h1 = (_Float16)v.y,
                           h2 = (_Float16)v.z, h3 = (_Float16)v.w;
            const f16x4 hv = {h0, h1, h2, h3};
            const f16x4 lv = {(_Float16)(v.x - (float)h0), (_Float16)(v.y - (float)h1),
                              (_Float16)(v.z - (float)h2), (_Float16)(v.w - (float)h3)};
            const int ks = (skh + i * 4) ^ sxor;
            *reinterpret_cast<f16x4*>(&Ah[srow * BK + ks]) = hv;
            *reinterpret_cast<f16x4*>(&Al[srow * BK + ks]) = lv;
        }
#pragma unroll
        for (int i = 0; i < 4; ++i) {
            const int ks = (skh + i * 8) ^ sxor;
            *reinterpret_cast<f16x8*>(&Bh[srow * BK + ks]) = bhv[i];
            *reinterpret_cast<f16x8*>(&Bl[srow * BK + ks]) = blv[i];
        }
        __syncthreads();
        // ---- issue next tile's global loads (latency hidden under MFMA)
        if (kt < 7) {
            const int k1 = (kt + 1) * BK;
#pragma unroll
            for (int i = 0; i < 8; ++i)
                av[i] = *reinterpret_cast<const float4*>(aptr0 + k1 + i * 4);
#pragma unroll
            for (int i = 0; i < 4; ++i) {
                bhv[i] = *reinterpret_cast<const f16x8*>(bhp0 + k1 + i * 8);
                blv[i] = *reinterpret_cast<const f16x8*>(blp0 + k1 + i * 8);
            }
        }
        // ---- compute: 2 mfma K-steps of 32
#pragma unroll
        for (int ks = 0; ks < 2; ++ks) {
            const int kf = (ks * 32 + fq * 8) ^ axor;
            f16x8 ah[4], al[4], bh[4], bl[4];
#pragma unroll
            for (int m = 0; m < 4; ++m) {
                const int r = wr * 64 + m * 16 + fr;
                ah[m] = *reinterpret_cast<const f16x8*>(&Ah[r * BK + kf]);
                al[m] = *reinterpret_cast<const f16x8*>(&Al[r * BK + kf]);
            }
#pragma unroll
            for (int n = 0; n < 4; ++n) {
                const int c = wc * 64 + n * 16 + fr;
                bh[n] = *reinterpret_cast<const f16x8*>(&Bh[c * BK + kf]);
                bl[n] = *reinterpret_cast<const f16x8*>(&Bl[c * BK + kf]);
            }
#pragma unroll
            for (int m = 0; m < 4; ++m)
#pragma unroll
                for (int n = 0; n < 4; ++n) {
                    acc[m][n] = __builtin_amdgcn_mfma_f32_16x16x32_f16(ah[m], bh[n], acc[m][n], 0, 0, 0);
                    acc[m][n] = __builtin_amdgcn_mfma_f32_16x16x32_f16(ah[m], bl[n], acc[m][n], 0, 0, 0);
                    acc[m][n] = __builtin_amdgcn_mfma_f32_16x16x32_f16(al[m], bh[n], acc[m][n], 0, 0, 0);
                }
        }
    }
    // ---- epilogue: C[row][col] = acc + bias[col]
    const int crow = row0 + wr * 64 + fq * 4;
    const int ccol = col0 + wc * 64 + fr;
#pragma unroll
    for (int n = 0; n < 4; ++n) {
        const float bv = bias ? bias[ccol + n * 16] : 0.f;
#pragma unroll
        for (int m = 0; m < 4; ++m)
#pragma unroll
            for (int j = 0; j < 4; ++j)
                C[(size_t)(crow + m * 16 + j) * IN_ + ccol + n * 16] = acc[m][n][j] + bv;
    }
}

// ------------------------------------------------------------- attention (fp32)
// grid (N/64, B*H), block 256. Q,K,V,P in LDS. Strides 68/68/81: rows 16B-
// aligned for float4 (b128) access; all read phases broadcast or <=2-way.
__global__ __launch_bounds__(256) void attn(const float* __restrict__ Q,
                                            const float* __restrict__ Kbuf,
                                            const float* __restrict__ Vbuf,
                                            float* __restrict__ Abuf) {
    __shared__ float Qs[64 * 68];
    __shared__ float KVs[77 * 68];
    __shared__ float P[64 * 81];
    const int tid = threadIdx.x;
    const int bh = blockIdx.y;
    const int b = bh >> 3, h = bh & 7;
    const int n0 = blockIdx.x * 64;

    {   // Q tile, pre-scaled by 1/sqrt(64)
        const float* qsrc = Q + ((size_t)b * N_ + n0) * IN_ + h * 64;
        for (int f4 = tid; f4 < 64 * 16; f4 += 256) {
            const int r = f4 >> 4, dq = (f4 & 15) << 2;
            const float4 v = *reinterpret_cast<const float4*>(&qsrc[(size_t)r * IN_ + dq]);
            Qs[r * 68 + dq + 0] = v.x * 0.125f;
            Qs[r * 68 + dq + 1] = v.y * 0.125f;
            Qs[r * 68 + dq + 2] = v.z * 0.125f;
            Qs[r * 68 + dq + 3] = v.w * 0.125f;
        }
    }
    {   // K tile
        const float* ksrc = Kbuf + (size_t)bh * M_ * DH_;
        for (int f = tid; f < M_ * DH_; f += 256)
            KVs[(f >> 6) * 68 + (f & 63)] = ksrc[f];
    }
    __syncthreads();

    // ---- scores: float4 over d. 16 rg x 16 mg, 4 rows x 5 cols per thread.
    const int rg = tid >> 4, mg = tid & 15;
    const int r0 = rg * 4, m0 = mg * 5;
    float s[4][5];
#pragma unroll
    for (int i = 0; i < 4; ++i)
#pragma unroll
        for (int jj = 0; jj < 5; ++jj) s[i][jj] = 0.f;
    for (int d0 = 0; d0 < 64; d0 += 4) {
        float4 qv[4];
#pragma unroll
        for (int i = 0; i < 4; ++i)
            qv[i] = *reinterpret_cast<const float4*>(&Qs[(r0 + i) * 68 + d0]);
#pragma unroll
        for (int jj = 0; jj < 5; ++jj) {
            const int mm = (m0 + jj < 77) ? (m0 + jj) : 76;  // clamp, masked later
            const float4 kv = *reinterpret_cast<const float4*>(&KVs[mm * 68 + d0]);
#pragma unroll
            for (int i = 0; i < 4; ++i) {
                s[i][jj] = fmaf(qv[i].x, kv.x, s[i][jj]);
                s[i][jj] = fmaf(qv[i].y, kv.y, s[i][jj]);
                s[i][jj] = fmaf(qv[i].z, kv.z, s[i][jj]);
                s[i][jj] = fmaf(qv[i].w, kv.w, s[i][jj]);
            }
        }
    }
    // ---- softmax per row across the 16 mg lanes (contiguous within wave)
#pragma unroll
    for (int i = 0; i < 4; ++i) {
        float mx = -1e30f;
#pragma unroll
        for (int jj = 0; jj < 5; ++jj)
            if (m0 + jj < 77) mx = fmaxf(mx, s[i][jj]);
        for (int off = 1; off < 16; off <<= 1) mx = fmaxf(mx, __shfl_xor(mx, off, 64));
        float p[5], sum = 0.f;
#pragma unroll
        for (int jj = 0; jj < 5; ++jj) {
            p[jj] = (m0 + jj < 77) ? __expf(s[i][jj] - mx) : 0.f;
            sum += p[jj];
        }
        for (int off = 1; off < 16; off <<= 1) sum += __shfl_xor(sum, off, 64);
        const float rs = 1.f / sum;
#pragma unroll
        for (int jj = 0; jj < 5; ++jj)
            if (m0 + jj < 77) P[(r0 + i) * 81 + m0 + jj] = p[jj] * rs;
    }
    __syncthreads();
    {   // V tile overwrites K
        const float* vsrc = Vbuf + (size_t)bh * M_ * DH_;
        for (int f = tid; f < M_ * DH_; f += 256)
            KVs[(f >> 6) * 68 + (f & 63)] = vsrc[f];
    }
    __syncthreads();
    // ---- PV: 16 rg x 16 dg, 4 rows x float4-of-d per thread
    const int d0v = mg * 4;
    float4 o[4];
#pragma unroll
    for (int i = 0; i < 4; ++i) o[i] = make_float4(0.f, 0.f, 0.f, 0.f);
    for (int m = 0; m < 77; ++m) {
        const float4 vv = *reinterpret_cast<const float4*>(&KVs[m * 68 + d0v]);
#pragma unroll
        for (int i = 0; i < 4; ++i) {
            const float pv = P[(r0 + i) * 81 + m];
            o[i].x = fmaf(pv, vv.x, o[i].x);
            o[i].y = fmaf(pv, vv.y, o[i].y);
            o[i].z = fmaf(pv, vv.z, o[i].z);
            o[i].w = fmaf(pv, vv.w, o[i].w);
        }
    }
    float* dst = Abuf + ((size_t)b * N_ + n0) * IN_ + h * 64;
#pragma unroll
    for (int i = 0; i < 4; ++i)
        *reinterpret_cast<float4*>(&dst[(size_t)(r0 + i) * IN_ + d0v]) = o[i];
}

extern "C" void kernel_launch(void* const* d_in, const int* in_sizes, int n_in,
                              void* d_out, int out_size, void* d_ws, size_t ws_size,
                              hipStream_t stream) {
    const float* x   = (const float*)d_in[0];
    const float* ctx = (const float*)d_in[1];
    const float* Wq  = (const float*)d_in[2];
    const float* Wk  = (const float*)d_in[3];
    const float* Wv  = (const float*)d_in[4];
    const float* Wo  = (const float*)d_in[5];
    const float* bo  = (const float*)d_in[6];
    float* out = (float*)d_out;

    // ws layout: Kbuf | Vbuf | Abuf | Wqt_hi | Wqt_lo | Wot_hi | Wot_lo (~72 MB)
    float* Kbuf = (float*)d_ws;
    float* Vbuf = Kbuf + (size_t)B_ * H_ * M_ * DH_;
    float* Abuf = Vbuf + (size_t)B_ * H_ * M_ * DH_;
    _Float16* qh = (_Float16*)(Abuf + (size_t)B_ * N_ * IN_);
    _Float16* ql = qh + (size_t)IN_ * IN_;
    _Float16* oh = ql + (size_t)IN_ * IN_;
    _Float16* ol = oh + (size_t)IN_ * IN_;

    wsplit<<<dim3(8, 8, 2), 256, 0, stream>>>(Wq, Wo, qh, ql, oh, ol);
    kv_proj<<<dim3(11, B_), 512, 0, stream>>>(ctx, Wk, Wv, Kbuf, Vbuf);
    // Q staged in d_out, then overwritten by final GEMM.
    gemm_mfma<<<1024, 256, 0, stream>>>(x, qh, ql, nullptr, out);
    attn<<<dim3(N_ / 64, B_ * H_), 256, 0, stream>>>(out, Kbuf, Vbuf, Abuf);
    gemm_mfma<<<1024, 256, 0, stream>>>(Abuf, oh, ol, bo, out);
}

// Round 9
// 445.539 us; speedup vs baseline: 2.3556x; 2.3556x over previous
//
#include <hip/hip_runtime.h>
#include <hip/hip_bf16.h>

constexpr int B_ = 8, N_ = 4096, M_ = 77;
constexpr int CD_ = 768, H_ = 8, DH_ = 64, IN_ = 512;

typedef _Float16 f16x4 __attribute__((ext_vector_type(4)));
typedef _Float16 f16x8 __attribute__((ext_vector_type(8)));
typedef float f32x4 __attribute__((ext_vector_type(4)));

// ------------------------------------------------------------- K/V projection
__global__ __launch_bounds__(512) void kv_proj(const float* __restrict__ ctx,
                                               const float* __restrict__ Wk,
                                               const float* __restrict__ Wv,
                                               float* __restrict__ Kbuf,
                                               float* __restrict__ Vbuf) {
    __shared__ float cs[7 * CD_];
    const int b = blockIdx.y;
    const int m0 = blockIdx.x * 7;
    const int tid = threadIdx.x;
    const float* src = ctx + ((size_t)b * M_ + m0) * CD_;
    for (int f = tid; f < 7 * CD_; f += 512) cs[f] = src[f];
    __syncthreads();
    float aK[7], aV[7];
#pragma unroll
    for (int i = 0; i < 7; ++i) { aK[i] = 0.f; aV[i] = 0.f; }
    const int j = tid;
    for (int c = 0; c < CD_; ++c) {
        const float wk = Wk[(size_t)c * IN_ + j];
        const float wv = Wv[(size_t)c * IN_ + j];
#pragma unroll
        for (int i = 0; i < 7; ++i) {
            aK[i] = fmaf(cs[i * CD_ + c], wk, aK[i]);
            aV[i] = fmaf(cs[i * CD_ + c], wv, aV[i]);
        }
    }
    const int h = j >> 6, d = j & 63;
#pragma unroll
    for (int i = 0; i < 7; ++i) {
        const size_t o = (((size_t)b * H_ + h) * M_ + (m0 + i)) * DH_ + d;
        Kbuf[o] = aK[i];
        Vbuf[o] = aV[i];
    }
}

// ------------------------------------------------------------- weight prep
__global__ __launch_bounds__(256) void wsplit(const float* __restrict__ Wq,
                                              const float* __restrict__ Wo,
                                              _Float16* __restrict__ qh, _Float16* __restrict__ ql,
                                              _Float16* __restrict__ oh, _Float16* __restrict__ ol) {
    __shared__ float T[64][65];
    const float* W = blockIdx.z ? Wo : Wq;
    _Float16* Hh = blockIdx.z ? oh : qh;
    _Float16* Hl = blockIdx.z ? ol : ql;
    const int k0 = blockIdx.y * 64, c0 = blockIdx.x * 64;
    const int tid = threadIdx.x;
    for (int f = tid; f < 4096; f += 256) {
        const int i = f >> 6, j = f & 63;
        T[i][j] = W[(size_t)(k0 + i) * IN_ + c0 + j];
    }
    __syncthreads();
    for (int f = tid; f < 4096; f += 256) {
        const int ci = f >> 6, kj = f & 63;
        const float v = T[kj][ci];
        const _Float16 h = (_Float16)v;
        const _Float16 l = (_Float16)(v - (float)h);
        Hh[(size_t)(c0 + ci) * IN_ + k0 + kj] = h;
        Hl[(size_t)(c0 + ci) * IN_ + k0 + kj] = l;
    }
}

// ------------------------------------------------------------- MFMA GEMM (unchanged, passed R8)
__global__ __launch_bounds__(256) void gemm_mfma(const float* __restrict__ A,
                                                 const _Float16* __restrict__ Wth,
                                                 const _Float16* __restrict__ Wtl,
                                                 const float* __restrict__ bias,
                                                 float* __restrict__ C) {
    constexpr int BK = 64;
    __shared__ __align__(16) _Float16 Ah[128 * BK];
    __shared__ __align__(16) _Float16 Al[128 * BK];
    __shared__ __align__(16) _Float16 Bh[128 * BK];
    __shared__ __align__(16) _Float16 Bl[128 * BK];
    const int tid = threadIdx.x;
    const int hw = blockIdx.x;
    const int logical = (hw & 7) * 128 + (hw >> 3);
    const int col0 = (logical & 3) * 128;
    const int row0 = (logical >> 2) * 128;
    const int lane = tid & 63;
    const int wid = tid >> 6;
    const int wr = wid >> 1, wc = wid & 1;
    const int fr = lane & 15, fq = lane >> 4;

    const int srow = tid >> 1;
    const int skh = (tid & 1) * 32;
    const int sxor = (srow & 7) << 3;
    const int axor = (fr & 7) << 3;

    const float* aptr0 = A + (size_t)(row0 + srow) * IN_ + skh;
    const _Float16* bhp0 = Wth + (size_t)(col0 + srow) * IN_ + skh;
    const _Float16* blp0 = Wtl + (size_t)(col0 + srow) * IN_ + skh;

    f32x4 acc[4][4];
#pragma unroll
    for (int m = 0; m < 4; ++m)
#pragma unroll
        for (int n = 0; n < 4; ++n) acc[m][n] = (f32x4){0.f, 0.f, 0.f, 0.f};

    float4 av[8];
    f16x8 bhv[4], blv[4];
#pragma unroll
    for (int i = 0; i < 8; ++i)
        av[i] = *reinterpret_cast<const float4*>(aptr0 + i * 4);
#pragma unroll
    for (int i = 0; i < 4; ++i) {
        bhv[i] = *reinterpret_cast<const f16x8*>(bhp0 + i * 8);
        blv[i] = *reinterpret_cast<const f16x8*>(blp0 + i * 8);
    }

#pragma unroll
    for (int kt = 0; kt < 8; ++kt) {
        __syncthreads();
#pragma unroll
        for (int i = 0; i < 8; ++i) {
            const float4 v = av[i];
            const _Float16 h0 = (_Float16)v.x, h1 = (_Float16)v.y,
                           h2 = (_Float16)v.z, h3 = (_Float16)v.w;
            const f16x4 hv = {h0, h1, h2, h3};
            const f16x4 lv = {(_Float16)(v.x - (float)h0), (_Float16)(v.y - (float)h1),
                              (_Float16)(v.z - (float)h2), (_Float16)(v.w - (float)h3)};
            const int ks = (skh + i * 4) ^ sxor;
            *reinterpret_cast<f16x4*>(&Ah[srow * BK + ks]) = hv;
            *reinterpret_cast<f16x4*>(&Al[srow * BK + ks]) = lv;
        }
#pragma unroll
        for (int i = 0; i < 4; ++i) {
            const int ks = (skh + i * 8) ^ sxor;
            *reinterpret_cast<f16x8*>(&Bh[srow * BK + ks]) = bhv[i];
            *reinterpret_cast<f16x8*>(&Bl[srow * BK + ks]) = blv[i];
        }
        __syncthreads();
        if (kt < 7) {
            const int k1 = (kt + 1) * BK;
#pragma unroll
            for (int i = 0; i < 8; ++i)
                av[i] = *reinterpret_cast<const float4*>(aptr0 + k1 + i * 4);
#pragma unroll
            for (int i = 0; i < 4; ++i) {
                bhv[i] = *reinterpret_cast<const f16x8*>(bhp0 + k1 + i * 8);
                blv[i] = *reinterpret_cast<const f16x8*>(blp0 + k1 + i * 8);
            }
        }
#pragma unroll
        for (int ks = 0; ks < 2; ++ks) {
            const int kf = (ks * 32 + fq * 8) ^ axor;
            f16x8 ah[4], al[4], bh[4], bl[4];
#pragma unroll
            for (int m = 0; m < 4; ++m) {
                const int r = wr * 64 + m * 16 + fr;
                ah[m] = *reinterpret_cast<const f16x8*>(&Ah[r * BK + kf]);
                al[m] = *reinterpret_cast<const f16x8*>(&Al[r * BK + kf]);
            }
#pragma unroll
            for (int n = 0; n < 4; ++n) {
                const int c = wc * 64 + n * 16 + fr;
                bh[n] = *reinterpret_cast<const f16x8*>(&Bh[c * BK + kf]);
                bl[n] = *reinterpret_cast<const f16x8*>(&Bl[c * BK + kf]);
            }
#pragma unroll
            for (int m = 0; m < 4; ++m)
#pragma unroll
                for (int n = 0; n < 4; ++n) {
                    acc[m][n] = __builtin_amdgcn_mfma_f32_16x16x32_f16(ah[m], bh[n], acc[m][n], 0, 0, 0);
                    acc[m][n] = __builtin_amdgcn_mfma_f32_16x16x32_f16(ah[m], bl[n], acc[m][n], 0, 0, 0);
                    acc[m][n] = __builtin_amdgcn_mfma_f32_16x16x32_f16(al[m], bh[n], acc[m][n], 0, 0, 0);
                }
        }
    }
    const int crow = row0 + wr * 64 + fq * 4;
    const int ccol = col0 + wc * 64 + fr;
#pragma unroll
    for (int n = 0; n < 4; ++n) {
        const float bv = bias ? bias[ccol + n * 16] : 0.f;
#pragma unroll
        for (int m = 0; m < 4; ++m)
#pragma unroll
            for (int j = 0; j < 4; ++j)
                C[(size_t)(crow + m * 16 + j) * IN_ + ccol + n * 16] = acc[m][n][j] + bv;
    }
}

// ------------------------------------------------------------- attention (MFMA split-f16)
// grid (64, 64), block 256 = 4 waves; wave w -> Q rows 16w..16w+15 of a 64-row tile.
// Phase1: S = (Q*0.125) K^T  (16x16x32, 3-product split). Softmax in-reg
// (D layout: row=fq*4+j, col=n*16+fr; 16-lane shfl groups). Phase2: O = P V.
// LDS: buf1 = Q[64][72] -> P[64][104]; buf2 = K[80][72] -> Vt[64][104]. 52 KB.
__global__ __launch_bounds__(256, 3) void attn_mfma(const float* __restrict__ Q,
                                                    const float* __restrict__ Kbuf,
                                                    const float* __restrict__ Vbuf,
                                                    float* __restrict__ Abuf) {
    constexpr int QS = 72;    // Q/K row stride (f16): 2-way banks max
    constexpr int PS = 104;   // P/Vt row stride
    __shared__ __align__(16) _Float16 buf1[2 * 64 * PS];
    __shared__ __align__(16) _Float16 buf2[2 * 64 * PS];
    _Float16* Qh = buf1;  _Float16* Ql = buf1 + 64 * PS;
    _Float16* Ph = buf1;  _Float16* Pl = buf1 + 64 * PS;
    _Float16* Kh = buf2;  _Float16* Kl = buf2 + 64 * PS;
    _Float16* Vth = buf2; _Float16* Vtl = buf2 + 64 * PS;

    const int tid = threadIdx.x;
    const int bh = blockIdx.y, b = bh >> 3, h = bh & 7;
    const int n0 = blockIdx.x * 64;
    const int lane = tid & 63, w = tid >> 6;
    const int fr = lane & 15, fq = lane >> 4;

    // ---- stage Q (pre-scaled) and K (zero-pad rows 77..79) as f16 hi/lo
    const float* qsrc = Q + ((size_t)b * N_ + n0) * IN_ + h * 64;
    for (int f4 = tid; f4 < 64 * 16; f4 += 256) {
        const int r = f4 >> 4, dq = (f4 & 15) * 4;
        float4 v = *reinterpret_cast<const float4*>(&qsrc[(size_t)r * IN_ + dq]);
        v.x *= 0.125f; v.y *= 0.125f; v.z *= 0.125f; v.w *= 0.125f;
        const _Float16 h0 = (_Float16)v.x, h1 = (_Float16)v.y,
                       h2 = (_Float16)v.z, h3 = (_Float16)v.w;
        *reinterpret_cast<f16x4*>(&Qh[r * QS + dq]) = (f16x4){h0, h1, h2, h3};
        *reinterpret_cast<f16x4*>(&Ql[r * QS + dq]) =
            (f16x4){(_Float16)(v.x - (float)h0), (_Float16)(v.y - (float)h1),
                    (_Float16)(v.z - (float)h2), (_Float16)(v.w - (float)h3)};
    }
    const float* ksrc = Kbuf + (size_t)bh * M_ * DH_;
    for (int f4 = tid; f4 < 80 * 16; f4 += 256) {
        const int m = f4 >> 4, dq = (f4 & 15) * 4;
        float4 v = make_float4(0.f, 0.f, 0.f, 0.f);
        if (m < 77) v = *reinterpret_cast<const float4*>(&ksrc[(size_t)m * DH_ + dq]);
        const _Float16 h0 = (_Float16)v.x, h1 = (_Float16)v.y,
                       h2 = (_Float16)v.z, h3 = (_Float16)v.w;
        *reinterpret_cast<f16x4*>(&Kh[m * QS + dq]) = (f16x4){h0, h1, h2, h3};
        *reinterpret_cast<f16x4*>(&Kl[m * QS + dq]) =
            (f16x4){(_Float16)(v.x - (float)h0), (_Float16)(v.y - (float)h1),
                    (_Float16)(v.z - (float)h2), (_Float16)(v.w - (float)h3)};
    }
    // ---- V -> regs now (latency hides under phase 1); m>=77 zeroed
    float4 vreg[6];
    const float* vsrc = Vbuf + (size_t)bh * M_ * DH_;
#pragma unroll
    for (int u = 0; u < 6; ++u) {
        const int f4 = tid + u * 256;
        const int m = f4 >> 4, dq = (f4 & 15) * 4;
        vreg[u] = (m < 77) ? *reinterpret_cast<const float4*>(&vsrc[(size_t)m * DH_ + dq])
                           : make_float4(0.f, 0.f, 0.f, 0.f);
    }
    __syncthreads();

    // ---- phase 1: scores (5 col-tiles x 2 k-steps x 3 products)
    f32x4 s[5];
#pragma unroll
    for (int n = 0; n < 5; ++n) s[n] = (f32x4){0.f, 0.f, 0.f, 0.f};
#pragma unroll
    for (int ks = 0; ks < 2; ++ks) {
        const int kf = ks * 32 + fq * 8;
        const f16x8 qh8 = *reinterpret_cast<const f16x8*>(&Qh[(w * 16 + fr) * QS + kf]);
        const f16x8 ql8 = *reinterpret_cast<const f16x8*>(&Ql[(w * 16 + fr) * QS + kf]);
#pragma unroll
        for (int n = 0; n < 5; ++n) {
            const f16x8 kh8 = *reinterpret_cast<const f16x8*>(&Kh[(n * 16 + fr) * QS + kf]);
            const f16x8 kl8 = *reinterpret_cast<const f16x8*>(&Kl[(n * 16 + fr) * QS + kf]);
            s[n] = __builtin_amdgcn_mfma_f32_16x16x32_f16(qh8, kh8, s[n], 0, 0, 0);
            s[n] = __builtin_amdgcn_mfma_f32_16x16x32_f16(qh8, kl8, s[n], 0, 0, 0);
            s[n] = __builtin_amdgcn_mfma_f32_16x16x32_f16(ql8, kh8, s[n], 0, 0, 0);
        }
    }
    // mask cols 77..79 (col = 64 + fr for n=4)
    if (fr >= 13) s[4] = (f32x4){-1e30f, -1e30f, -1e30f, -1e30f};

    // ---- softmax (rows = fq*4+j; reduce over 16-lane fr group x 5 regs)
    float rs[4];
#pragma unroll
    for (int j = 0; j < 4; ++j) {
        float mx = s[0][j];
#pragma unroll
        for (int n = 1; n < 5; ++n) mx = fmaxf(mx, s[n][j]);
        for (int off = 1; off < 16; off <<= 1) mx = fmaxf(mx, __shfl_xor(mx, off, 64));
        float sum = 0.f;
#pragma unroll
        for (int n = 0; n < 5; ++n) {
            const float p = __expf(s[n][j] - mx);
            s[n][j] = p;           // keep unnormalized P in regs
            sum += p;
        }
        for (int off = 1; off < 16; off <<= 1) sum += __shfl_xor(sum, off, 64);
        rs[j] = 1.f / sum;
    }
    __syncthreads();   // all waves done reading Q/K

    // ---- write P (hi/lo), zero P cols 80..95, stage Vt (transposed V) hi/lo
#pragma unroll
    for (int j = 0; j < 4; ++j) {
        const int row = w * 16 + fq * 4 + j;
#pragma unroll
        for (int n = 0; n < 5; ++n) {
            const float p = s[n][j];
            const _Float16 ph = (_Float16)p;
            Ph[row * PS + n * 16 + fr] = ph;
            Pl[row * PS + n * 16 + fr] = (_Float16)(p - (float)ph);
        }
    }
    for (int idx = tid; idx < 64 * 16; idx += 256) {
        const int r = idx >> 4, c = 80 + (idx & 15);
        Ph[r * PS + c] = (_Float16)0.f;
        Pl[r * PS + c] = (_Float16)0.f;
    }
#pragma unroll
    for (int u = 0; u < 6; ++u) {
        const int f4 = tid + u * 256;
        const int m = f4 >> 4, dq = (f4 & 15) * 4;
        const float4 v = vreg[u];
#pragma unroll
        for (int c = 0; c < 4; ++c) {
            const float val = (&v.x)[c];
            const _Float16 hh = (_Float16)val;
            Vth[(dq + c) * PS + m] = hh;
            Vtl[(dq + c) * PS + m] = (_Float16)(val - (float)hh);
        }
    }
    __syncthreads();

    // ---- phase 2: O = P V  (4 col-tiles x 3 k-steps x 3 products)
    f32x4 o[4];
#pragma unroll
    for (int n = 0; n < 4; ++n) o[n] = (f32x4){0.f, 0.f, 0.f, 0.f};
#pragma unroll
    for (int ks = 0; ks < 3; ++ks) {
        const int kf = ks * 32 + fq * 8;
        const f16x8 ph8 = *reinterpret_cast<const f16x8*>(&Ph[(w * 16 + fr) * PS + kf]);
        const f16x8 pl8 = *reinterpret_cast<const f16x8*>(&Pl[(w * 16 + fr) * PS + kf]);
#pragma unroll
        for (int n = 0; n < 4; ++n) {
            const f16x8 vh8 = *reinterpret_cast<const f16x8*>(&Vth[(n * 16 + fr) * PS + kf]);
            const f16x8 vl8 = *reinterpret_cast<const f16x8*>(&Vtl[(n * 16 + fr) * PS + kf]);
            o[n] = __builtin_amdgcn_mfma_f32_16x16x32_f16(ph8, vh8, o[n], 0, 0, 0);
            o[n] = __builtin_amdgcn_mfma_f32_16x16x32_f16(ph8, vl8, o[n], 0, 0, 0);
            o[n] = __builtin_amdgcn_mfma_f32_16x16x32_f16(pl8, vh8, o[n], 0, 0, 0);
        }
    }
    // ---- store (normalize by rs[j]); lanes same (fq,j) -> 16 consecutive floats
    float* dst = Abuf + ((size_t)b * N_ + n0 + w * 16) * IN_ + h * 64;
#pragma unroll
    for (int n = 0; n < 4; ++n)
#pragma unroll
        for (int j = 0; j < 4; ++j)
            dst[(size_t)(fq * 4 + j) * IN_ + n * 16 + fr] = o[n][j] * rs[j];
}

extern "C" void kernel_launch(void* const* d_in, const int* in_sizes, int n_in,
                              void* d_out, int out_size, void* d_ws, size_t ws_size,
                              hipStream_t stream) {
    const float* x   = (const float*)d_in[0];
    const float* ctx = (const float*)d_in[1];
    const float* Wq  = (const float*)d_in[2];
    const float* Wk  = (const float*)d_in[3];
    const float* Wv  = (const float*)d_in[4];
    const float* Wo  = (const float*)d_in[5];
    const float* bo  = (const float*)d_in[6];
    float* out = (float*)d_out;

    float* Kbuf = (float*)d_ws;
    float* Vbuf = Kbuf + (size_t)B_ * H_ * M_ * DH_;
    float* Abuf = Vbuf + (size_t)B_ * H_ * M_ * DH_;
    _Float16* qh = (_Float16*)(Abuf + (size_t)B_ * N_ * IN_);
    _Float16* ql = qh + (size_t)IN_ * IN_;
    _Float16* oh = ql + (size_t)IN_ * IN_;
    _Float16* ol = oh + (size_t)IN_ * IN_;

    wsplit<<<dim3(8, 8, 2), 256, 0, stream>>>(Wq, Wo, qh, ql, oh, ol);
    kv_proj<<<dim3(11, B_), 512, 0, stream>>>(ctx, Wk, Wv, Kbuf, Vbuf);
    gemm_mfma<<<1024, 256, 0, stream>>>(x, qh, ql, nullptr, out);
    attn_mfma<<<dim3(N_ / 64, B_ * H_), 256, 0, stream>>>(out, Kbuf, Vbuf, Abuf);
    gemm_mfma<<<1024, 256, 0, stream>>>(Abuf, oh, ol, bo, out);
}